// Round 1
// baseline (1814.138 us; speedup 1.0000x reference)
//
#include <hip/hip_runtime.h>

// Problem constants (B,C,H,W) = (4,32,512,960), fp32 everywhere.
#define BB 4
#define CC 32
#define HH 512
#define WW 960
#define HWSZ (HH * WW)          // 491520
#define NPIX (BB * HWSZ)        // 1966080 source pixels
#define CS 36                   // channel stride in acc (32 num + 1 den + pad), 144B: 16B-aligned

// ---------------- fast path: channel-last accumulator in d_ws ----------------
// One 32-lane group per source pixel; lane = channel. Per corner, the 32
// atomics are contiguous (128B) -> coalesced at TCC. Lane 0 also adds em
// (denominator) at slot 32.
__global__ __launch_bounds__(512) void splat_soa(
    const float* __restrict__ inp, const float* __restrict__ flow,
    const float* __restrict__ metric, const float* __restrict__ beta,
    float* __restrict__ acc)
{
    int t   = blockIdx.x * 512 + threadIdx.x;
    int c   = t & 31;
    int pix = t >> 5;                 // [0, NPIX)
    int b   = pix / HWSZ;
    int rem = pix - b * HWSZ;
    int y   = rem / WW;
    int x   = rem - y * WW;

    float flx = flow[(size_t)b * 2 * HWSZ + rem];
    float fly = flow[(size_t)b * 2 * HWSZ + HWSZ + rem];
    float m   = metric[(size_t)b * HWSZ + rem];
    float em  = expf(beta[0] * m);

    float ox = (float)x + flx;
    float oy = (float)y + fly;
    float x0f = floorf(ox), y0f = floorf(oy);
    int   x0 = (int)x0f,   y0 = (int)y0f;
    int   x1 = x0 + 1,     y1 = y0 + 1;
    float fx = ox - x0f,   fy = oy - y0f;
    float gx = 1.0f - fx,  gy = 1.0f - fy;

    float val = inp[((size_t)b * CC + c) * HWSZ + rem] * em;
    float* ab = acc + (size_t)b * HWSZ * CS;

#define DO_CORNER(CX, CY, WGT)                                        \
    if ((unsigned)(CX) < (unsigned)WW && (unsigned)(CY) < (unsigned)HH) { \
        float* p = ab + ((size_t)(CY) * WW + (CX)) * CS;              \
        atomicAdd(p + c, val * (WGT));                                \
        if (c == 0) atomicAdd(p + 32, em * (WGT));                    \
    }
    DO_CORNER(x0, y0, gx * gy)
    DO_CORNER(x1, y0, fx * gy)
    DO_CORNER(x0, y1, gx * fy)
    DO_CORNER(x1, y1, fx * fy)
#undef DO_CORNER
}

// Normalize: thread per target pixel, vectorized 144B read, 32 coalesced
// plane writes.
__global__ __launch_bounds__(256) void norm_soa(
    const float* __restrict__ acc, float* __restrict__ out)
{
    int pix = blockIdx.x * 256 + threadIdx.x;
    if (pix >= NPIX) return;
    int b   = pix / HWSZ;
    int rem = pix - b * HWSZ;

    const float4* p = (const float4*)(acc + (size_t)pix * CS);
    float4 v[9];
#pragma unroll
    for (int i = 0; i < 9; ++i) v[i] = p[i];
    float den = v[8].x;                 // slot 32
    if (den == 0.0f) den = 1.0f;

    const float* vf = (const float*)v;
    float* ob = out + (size_t)b * CC * HWSZ + rem;
#pragma unroll
    for (int c = 0; c < CC; ++c)
        ob[(size_t)c * HWSZ] = vf[c] / den;
}

// ---------------- fallback path (ws too small): planar atomics into d_out --
__global__ __launch_bounds__(512) void splat_planar(
    const float* __restrict__ inp, const float* __restrict__ flow,
    const float* __restrict__ metric, const float* __restrict__ beta,
    float* __restrict__ out, float* __restrict__ den)
{
    int t   = blockIdx.x * 512 + threadIdx.x;
    int c   = t & 31;
    int pix = t >> 5;
    int b   = pix / HWSZ;
    int rem = pix - b * HWSZ;
    int y   = rem / WW;
    int x   = rem - y * WW;

    float flx = flow[(size_t)b * 2 * HWSZ + rem];
    float fly = flow[(size_t)b * 2 * HWSZ + HWSZ + rem];
    float m   = metric[(size_t)b * HWSZ + rem];
    float em  = expf(beta[0] * m);

    float ox = (float)x + flx;
    float oy = (float)y + fly;
    float x0f = floorf(ox), y0f = floorf(oy);
    int   x0 = (int)x0f,   y0 = (int)y0f;
    int   x1 = x0 + 1,     y1 = y0 + 1;
    float fx = ox - x0f,   fy = oy - y0f;
    float gx = 1.0f - fx,  gy = 1.0f - fy;

    float val = inp[((size_t)b * CC + c) * HWSZ + rem] * em;

#define DO_CORNER(CX, CY, WGT)                                        \
    if ((unsigned)(CX) < (unsigned)WW && (unsigned)(CY) < (unsigned)HH) { \
        size_t ti = (size_t)(CY) * WW + (CX);                         \
        atomicAdd(out + ((size_t)b * CC + c) * HWSZ + ti, val * (WGT)); \
        if (c == 0) atomicAdd(den + (size_t)b * HWSZ + ti, em * (WGT)); \
    }
    DO_CORNER(x0, y0, gx * gy)
    DO_CORNER(x1, y0, fx * gy)
    DO_CORNER(x0, y1, gx * fy)
    DO_CORNER(x1, y1, fx * fy)
#undef DO_CORNER
}

__global__ __launch_bounds__(256) void norm_planar(
    float* __restrict__ out, const float* __restrict__ den)
{
    int pix = blockIdx.x * 256 + threadIdx.x;
    if (pix >= NPIX) return;
    int b   = pix / HWSZ;
    int rem = pix - b * HWSZ;
    float d = den[pix];
    if (d == 0.0f) d = 1.0f;
    float* ob = out + (size_t)b * CC * HWSZ + rem;
#pragma unroll
    for (int c = 0; c < CC; ++c)
        ob[(size_t)c * HWSZ] /= d;
}

extern "C" void kernel_launch(void* const* d_in, const int* in_sizes, int n_in,
                              void* d_out, int out_size, void* d_ws, size_t ws_size,
                              hipStream_t stream) {
    const float* inp    = (const float*)d_in[0];
    const float* flow   = (const float*)d_in[1];
    const float* metric = (const float*)d_in[2];
    const float* beta   = (const float*)d_in[3];
    float* out = (float*)d_out;

    const size_t need = (size_t)NPIX * CS * sizeof(float);   // ~283 MB

    if (ws_size >= need) {
        hipMemsetAsync(d_ws, 0, need, stream);
        // 512 threads = 16 source pixels/block; NPIX/16 = 122880 blocks exactly.
        splat_soa<<<NPIX / 16, 512, 0, stream>>>(inp, flow, metric, beta,
                                                 (float*)d_ws);
        norm_soa<<<(NPIX + 255) / 256, 256, 0, stream>>>((const float*)d_ws, out);
    } else {
        hipMemsetAsync(d_out, 0, (size_t)NPIX * CC * sizeof(float), stream);
        hipMemsetAsync(d_ws, 0, (size_t)NPIX * sizeof(float), stream);
        splat_planar<<<NPIX / 16, 512, 0, stream>>>(inp, flow, metric, beta,
                                                    out, (float*)d_ws);
        norm_planar<<<(NPIX + 255) / 256, 256, 0, stream>>>(out, (const float*)d_ws);
    }
}

// Round 3
// 1634.573 us; speedup vs baseline: 1.1099x; 1.1099x over previous
//
#include <hip/hip_runtime.h>

// (B,C,H,W) = (4,32,512,960), fp32.
#define BB 4
#define CC 32
#define HH 512
#define WW 960
#define HWSZ (HH * WW)          // 491520
#define NPIX (BB * HWSZ)        // 1966080 source pixels

// Grid-stride config: 1024 blocks x 512 threads = 16384 pixel-slots (32 lanes each)
#define NSLOT 16384
#define ITERS (NPIX / NSLOT)    // 120 exactly

// ---------------- splat: grid-stride, software-pipelined, split layout -------
// num: [NPIX][32] floats (128B/pixel, aligned -> each corner's 32-lane atomic
//      burst is exactly 2 full cache lines). den: [NPIX] floats, compact.
__global__ __launch_bounds__(512) void splat2(
    const float* __restrict__ inp, const float* __restrict__ flow,
    const float* __restrict__ metric, const float* __restrict__ beta,
    float* __restrict__ num, float* __restrict__ den)
{
    const float bta = beta[0];
    int t    = blockIdx.x * 512 + threadIdx.x;
    int c    = t & 31;
    int slot = t >> 5;                    // [0, NSLOT)

    // ---- prologue: load iteration 0 ----
    int pix = slot;
    int b   = pix / HWSZ;
    int rem = pix - b * HWSZ;
    float flx = flow[(size_t)b * 2 * HWSZ + rem];
    float fly = flow[(size_t)b * 2 * HWSZ + HWSZ + rem];
    float m   = metric[(size_t)b * HWSZ + rem];
    float vin = inp[((size_t)b * CC + c) * HWSZ + rem];

    for (int it = 0; it < ITERS; ++it) {
        // current values
        float cflx = flx, cfly = fly, cm = m, cvin = vin;
        int cpix = pix, cb = b, crem = rem;

        // ---- preload next iteration (hides latency under atomics) ----
        pix = cpix + NSLOT;
        if (it + 1 < ITERS) {
            b   = pix / HWSZ;
            rem = pix - b * HWSZ;
            flx = flow[(size_t)b * 2 * HWSZ + rem];
            fly = flow[(size_t)b * 2 * HWSZ + HWSZ + rem];
            m   = metric[(size_t)b * HWSZ + rem];
            vin = inp[((size_t)b * CC + c) * HWSZ + rem];
        }

        // ---- compute + scatter current ----
        int y = crem / WW;
        int x = crem - y * WW;
        float em = expf(bta * cm);
        float ox = (float)x + cflx;
        float oy = (float)y + cfly;
        float x0f = floorf(ox), y0f = floorf(oy);
        int   x0 = (int)x0f,   y0 = (int)y0f;
        int   x1 = x0 + 1,     y1 = y0 + 1;
        float fx = ox - x0f,   fy = oy - y0f;
        float gx = 1.0f - fx,  gy = 1.0f - fy;

        float val = cvin * em;
        size_t base = (size_t)cb * HWSZ;

#define DO_CORNER(CX, CY, WGT)                                            \
        if ((unsigned)(CX) < (unsigned)WW && (unsigned)(CY) < (unsigned)HH) { \
            size_t ti = base + (size_t)(CY) * WW + (CX);                  \
            atomicAdd(num + ti * CC + c, val * (WGT));                    \
            if (c == 0) atomicAdd(den + ti, em * (WGT));                  \
        }
        DO_CORNER(x0, y0, gx * gy)
        DO_CORNER(x1, y0, fx * gy)
        DO_CORNER(x0, y1, gx * fy)
        DO_CORNER(x1, y1, fx * fy)
#undef DO_CORNER
    }
}

// ---------------- normalize: channel-last num -> planar out -----------------
__global__ __launch_bounds__(256) void norm2(
    const float* __restrict__ num, const float* __restrict__ den,
    float* __restrict__ out)
{
    int pix = blockIdx.x * 256 + threadIdx.x;
    if (pix >= NPIX) return;
    int b   = pix / HWSZ;
    int rem = pix - b * HWSZ;

    const float4* p = (const float4*)(num + (size_t)pix * CC);
    float4 v[8];
#pragma unroll
    for (int i = 0; i < 8; ++i) v[i] = p[i];
    float d = den[pix];
    if (d == 0.0f) d = 1.0f;
    float inv = 1.0f / d;

    const float* vf = (const float*)v;
    float* ob = out + (size_t)b * CC * HWSZ + rem;
#pragma unroll
    for (int c = 0; c < CC; ++c)
        ob[(size_t)c * HWSZ] = vf[c] * inv;
}

// ---------------- fallback path (ws too small): planar atomics into d_out --
__global__ __launch_bounds__(512) void splat_planar(
    const float* __restrict__ inp, const float* __restrict__ flow,
    const float* __restrict__ metric, const float* __restrict__ beta,
    float* __restrict__ out, float* __restrict__ den)
{
    int t   = blockIdx.x * 512 + threadIdx.x;
    int c   = t & 31;
    int pix = t >> 5;
    int b   = pix / HWSZ;
    int rem = pix - b * HWSZ;
    int y   = rem / WW;
    int x   = rem - y * WW;

    float flx = flow[(size_t)b * 2 * HWSZ + rem];
    float fly = flow[(size_t)b * 2 * HWSZ + HWSZ + rem];
    float m   = metric[(size_t)b * HWSZ + rem];
    float em  = expf(beta[0] * m);

    float ox = (float)x + flx;
    float oy = (float)y + fly;
    float x0f = floorf(ox), y0f = floorf(oy);
    int   x0 = (int)x0f,   y0 = (int)y0f;
    int   x1 = x0 + 1,     y1 = y0 + 1;
    float fx = ox - x0f,   fy = oy - y0f;
    float gx = 1.0f - fx,  gy = 1.0f - fy;

    float val = inp[((size_t)b * CC + c) * HWSZ + rem] * em;

#define DO_CORNER(CX, CY, WGT)                                        \
    if ((unsigned)(CX) < (unsigned)WW && (unsigned)(CY) < (unsigned)HH) { \
        size_t ti = (size_t)(CY) * WW + (CX);                         \
        atomicAdd(out + ((size_t)b * CC + c) * HWSZ + ti, val * (WGT)); \
        if (c == 0) atomicAdd(den + (size_t)b * HWSZ + ti, em * (WGT)); \
    }
    DO_CORNER(x0, y0, gx * gy)
    DO_CORNER(x1, y0, fx * gy)
    DO_CORNER(x0, y1, gx * fy)
    DO_CORNER(x1, y1, fx * fy)
#undef DO_CORNER
}

__global__ __launch_bounds__(256) void norm_planar(
    float* __restrict__ out, const float* __restrict__ den)
{
    int pix = blockIdx.x * 256 + threadIdx.x;
    if (pix >= NPIX) return;
    int b   = pix / HWSZ;
    int rem = pix - b * HWSZ;
    float d = den[pix];
    if (d == 0.0f) d = 1.0f;
    float* ob = out + (size_t)b * CC * HWSZ + rem;
#pragma unroll
    for (int c = 0; c < CC; ++c)
        ob[(size_t)c * HWSZ] /= d;
}

extern "C" void kernel_launch(void* const* d_in, const int* in_sizes, int n_in,
                              void* d_out, int out_size, void* d_ws, size_t ws_size,
                              hipStream_t stream) {
    const float* inp    = (const float*)d_in[0];
    const float* flow   = (const float*)d_in[1];
    const float* metric = (const float*)d_in[2];
    const float* beta   = (const float*)d_in[3];
    float* out = (float*)d_out;

    const size_t num_bytes = (size_t)NPIX * CC * sizeof(float);  // 252 MB
    const size_t den_bytes = (size_t)NPIX * sizeof(float);       // 7.9 MB
    const size_t need = num_bytes + den_bytes;                   // ~260 MB

    if (ws_size >= need) {
        float* num = (float*)d_ws;
        float* den = (float*)((char*)d_ws + num_bytes);
        hipMemsetAsync(d_ws, 0, need, stream);
        splat2<<<NSLOT * 32 / 512, 512, 0, stream>>>(inp, flow, metric, beta,
                                                     num, den);
        norm2<<<NPIX / 256, 256, 0, stream>>>(num, den, out);
    } else {
        hipMemsetAsync(d_out, 0, (size_t)NPIX * CC * sizeof(float), stream);
        hipMemsetAsync(d_ws, 0, (size_t)NPIX * sizeof(float), stream);
        splat_planar<<<NPIX / 16, 512, 0, stream>>>(inp, flow, metric, beta,
                                                    out, (float*)d_ws);
        norm_planar<<<NPIX / 256, 256, 0, stream>>>(out, (const float*)d_ws);
    }
}